// Round 10
// baseline (17.593 us; speedup 1.0000x reference)
//
#include <hip/hip_runtime.h>

#define HW 56
#define PLANE 3136     // 56*56
#define CH 64          // channels after pair-sum
#define CI 32          // output channels
#define NI 2           // output channels per thread
#define WPAIRS 28      // float2 groups per row
#define P2 (HW*WPAIRS) // 1568 float2 pixel-groups

// Single kernel: inline pair-sum + 3-tap H conv + fused roll.
// grid = (7, 16), block = 256. 7*256 = 1792 >= 1568 pixel-pairs; each thread
// computes 2 adjacent-w pixels x 2 adjacent output channels. 448 waves.
__global__ __launch_bounds__(256) void convshift_kernel(
    const float* __restrict__ x, const float* __restrict__ Wt, float* __restrict__ out)
{
    __shared__ float sW[NI * CH * 3];            // 384 floats
    const int i0  = blockIdx.y * NI;
    const int tid = threadIdx.x;
    #pragma unroll
    for (int t = tid; t < NI * CH * 3; t += 256)
        sW[t] = Wt[i0 * (CH * 3) + t];
    __syncthreads();

    const int p  = blockIdx.x * 256 + tid;
    const int pc = (p < P2) ? p : (P2 - 1);     // clamp tail threads to safe addrs
    const int h  = pc / WPAIRS;
    const int wp = pc - h * WPAIRS;
    const int w0 = wp * 2;

    const bool v0 = (h > 0), v2 = (h < HW - 1);
    const int hm = v0 ? h - 1 : 0;              // clamped rows; masked at end
    const int hp = v2 ? h + 1 : HW - 1;

    const float* __restrict__ a0p = x + hm * HW + w0;              // first-half channels
    const float* __restrict__ a1p = x + h  * HW + w0;
    const float* __restrict__ a2p = x + hp * HW + w0;
    const float* __restrict__ b0p = a0p + CH * PLANE;              // second-half channels
    const float* __restrict__ b1p = a1p + CH * PLANE;
    const float* __restrict__ b2p = a2p + CH * PLANE;

    // accumulators: [i][tap] float2; merged + masked at end
    float2 acc[NI][3];
    #pragma unroll
    for (int ii = 0; ii < NI; ++ii)
        #pragma unroll
        for (int t = 0; t < 3; ++t)
            acc[ii][t] = make_float2(0.f, 0.f);

    // double-buffered register staging: 4 channels x 3 rows x 2 halves (float2)
    float2 A0[2][4], A1[2][4], A2[2][4], B0[2][4], B1[2][4], B2[2][4];

    #pragma unroll
    for (int j = 0; j < 4; ++j) {
        const int o = j * PLANE;
        A0[0][j] = *(const float2*)(a0p + o);
        A1[0][j] = *(const float2*)(a1p + o);
        A2[0][j] = *(const float2*)(a2p + o);
        B0[0][j] = *(const float2*)(b0p + o);
        B1[0][j] = *(const float2*)(b1p + o);
        B2[0][j] = *(const float2*)(b2p + o);
    }

    #pragma unroll
    for (int ch = 0; ch < 16; ++ch) {
        const int cur = ch & 1, nxt = cur ^ 1;
        if (ch < 15) {
            #pragma unroll
            for (int j = 0; j < 4; ++j) {
                const int o = ((ch + 1) * 4 + j) * PLANE;
                A0[nxt][j] = *(const float2*)(a0p + o);
                A1[nxt][j] = *(const float2*)(a1p + o);
                A2[nxt][j] = *(const float2*)(a2p + o);
                B0[nxt][j] = *(const float2*)(b0p + o);
                B1[nxt][j] = *(const float2*)(b1p + o);
                B2[nxt][j] = *(const float2*)(b2p + o);
            }
        }
        #pragma unroll
        for (int j = 0; j < 4; ++j) {
            const int c = ch * 4 + j;
            // pair-sum once, reuse across NI output channels
            float2 s0, s1, s2;
            s0.x = A0[cur][j].x + B0[cur][j].x;  s0.y = A0[cur][j].y + B0[cur][j].y;
            s1.x = A1[cur][j].x + B1[cur][j].x;  s1.y = A1[cur][j].y + B1[cur][j].y;
            s2.x = A2[cur][j].x + B2[cur][j].x;  s2.y = A2[cur][j].y + B2[cur][j].y;
            #pragma unroll
            for (int ii = 0; ii < NI; ++ii) {
                const float wk0 = sW[ii * (CH * 3) + c * 3 + 0];
                const float wk1 = sW[ii * (CH * 3) + c * 3 + 1];
                const float wk2 = sW[ii * (CH * 3) + c * 3 + 2];
                acc[ii][0].x += s0.x * wk0;  acc[ii][0].y += s0.y * wk0;
                acc[ii][1].x += s1.x * wk1;  acc[ii][1].y += s1.y * wk1;
                acc[ii][2].x += s2.x * wk2;  acc[ii][2].y += s2.y * wk2;
            }
        }
    }

    if (p < P2) {
        #pragma unroll
        for (int ii = 0; ii < NI; ++ii) {
            float rx = acc[ii][1].x, ry = acc[ii][1].y;
            if (v0) { rx += acc[ii][0].x; ry += acc[ii][0].y; }
            if (v2) { rx += acc[ii][2].x; ry += acc[ii][2].y; }
            // fuse jnp.roll(+1, axis=w): value at w stored at w+1
            float* orow = out + (i0 + ii) * PLANE + h * HW;
            orow[w0 + 1] = rx;                   // w0+1 <= 55, never wraps
            int ws2 = w0 + 2; if (ws2 == HW) ws2 = 0;
            orow[ws2] = ry;
        }
    }
}

extern "C" void kernel_launch(void* const* d_in, const int* in_sizes, int n_in,
                              void* d_out, int out_size, void* d_ws, size_t ws_size,
                              hipStream_t stream) {
    const float* x  = (const float*)d_in[0];   // (1,128,56,56) f32
    const float* Wt = (const float*)d_in[1];   // (32,64,3) f32
    float* out = (float*)d_out;                // (1,32,56,56) f32

    dim3 grid(7, CI / NI), block(256);
    hipLaunchKernelGGL(convshift_kernel, grid, block, 0, stream, x, Wt, out);
}

// Round 11
// 10.431 us; speedup vs baseline: 1.6866x; 1.6866x over previous
//
#include <hip/hip_runtime.h>

#define HW 56
#define PLANE 3136     // 56*56
#define CH 64          // channels after pair-sum
#define CI 32          // output channels
#define NI 2           // output channels per block (and per final store thread)
#define NQ 4           // channel quarters (one wave each)
#define CQ (CH/NQ)     // 16 channels per quarter

// Split-channel kernel: block = 256 = 64 pixels x 4 channel-quarters.
// Each wave computes a 16-channel partial for 64 pixels; LDS reduce; store.
// grid = (49, 16): 49*64 = 3136 pixels exact, 16 i-groups x NI=2. 3136 waves.
__global__ __launch_bounds__(256) void convshift_kernel(
    const float* __restrict__ x, const float* __restrict__ Wt, float* __restrict__ out)
{
    __shared__ float sW[NI * CH * 3];    // 384 floats
    __shared__ float red[NQ][NI][64];    // 2 KB partial sums

    const int i0  = blockIdx.y * NI;
    const int tid = threadIdx.x;
    #pragma unroll
    for (int t = tid; t < NI * CH * 3; t += 256)
        sW[t] = Wt[i0 * (CH * 3) + t];
    __syncthreads();

    const int px = tid & 63;             // pixel lane within block
    const int q  = tid >> 6;             // channel quarter = wave id
    const int p  = blockIdx.x * 64 + px; // 0..3135, exact cover
    const int h  = p / HW;
    const int w  = p - h * HW;

    const bool v0 = (h > 0), v2 = (h < HW - 1);
    const int hm = v0 ? h - 1 : 0;       // clamped rows; masked before reduction
    const int hp = v2 ? h + 1 : HW - 1;

    const int c0 = q * CQ;
    const float* __restrict__ xa = x + c0 * PLANE + w;          // first-half channels
    const float* __restrict__ xb = x + (CH + c0) * PLANE + w;   // second-half channels
    const int r0 = hm * HW, r1 = h * HW, r2 = hp * HW;

    float acc[NI][3];
    #pragma unroll
    for (int ii = 0; ii < NI; ++ii) { acc[ii][0] = 0.f; acc[ii][1] = 0.f; acc[ii][2] = 0.f; }

    // double-buffered register staging: 8 channels x 3 rows x 2 halves in flight
    float A0[2][8], A1[2][8], A2[2][8], B0[2][8], B1[2][8], B2[2][8];

    #pragma unroll
    for (int j = 0; j < 8; ++j) {
        const int o = j * PLANE;
        A0[0][j] = xa[o + r0]; A1[0][j] = xa[o + r1]; A2[0][j] = xa[o + r2];
        B0[0][j] = xb[o + r0]; B1[0][j] = xb[o + r1]; B2[0][j] = xb[o + r2];
    }

    #pragma unroll
    for (int chk = 0; chk < 2; ++chk) {
        const int cur = chk & 1, nxt = cur ^ 1;
        if (chk < 1) {
            #pragma unroll
            for (int j = 0; j < 8; ++j) {
                const int o = (8 + j) * PLANE;
                A0[nxt][j] = xa[o + r0]; A1[nxt][j] = xa[o + r1]; A2[nxt][j] = xa[o + r2];
                B0[nxt][j] = xb[o + r0]; B1[nxt][j] = xb[o + r1]; B2[nxt][j] = xb[o + r2];
            }
        }
        #pragma unroll
        for (int j = 0; j < 8; ++j) {
            const int ca = c0 + chk * 8 + j;          // absolute channel for weights
            const float s0 = A0[cur][j] + B0[cur][j]; // pair-sum once
            const float s1 = A1[cur][j] + B1[cur][j];
            const float s2 = A2[cur][j] + B2[cur][j];
            #pragma unroll
            for (int ii = 0; ii < NI; ++ii) {
                acc[ii][0] += s0 * sW[ii * (CH * 3) + ca * 3 + 0];
                acc[ii][1] += s1 * sW[ii * (CH * 3) + ca * 3 + 1];
                acc[ii][2] += s2 * sW[ii * (CH * 3) + ca * 3 + 2];
            }
        }
    }

    // mask boundary taps, deposit partials
    #pragma unroll
    for (int ii = 0; ii < NI; ++ii) {
        float r = acc[ii][1];
        if (v0) r += acc[ii][0];
        if (v2) r += acc[ii][2];
        red[q][ii][px] = r;
    }
    __syncthreads();

    // 128 threads: sum the 4 quarter-partials and store with fused roll
    if (tid < NI * 64) {
        const int ii  = tid >> 6;
        const int px2 = tid & 63;
        const float s = (red[0][ii][px2] + red[1][ii][px2])
                      + (red[2][ii][px2] + red[3][ii][px2]);
        const int p2 = blockIdx.x * 64 + px2;
        const int h2 = p2 / HW;
        const int w2 = p2 - h2 * HW;
        int wst = w2 + 1; if (wst == HW) wst = 0;   // fuse jnp.roll(+1, axis=w)
        out[(i0 + ii) * PLANE + h2 * HW + wst] = s;
    }
}

extern "C" void kernel_launch(void* const* d_in, const int* in_sizes, int n_in,
                              void* d_out, int out_size, void* d_ws, size_t ws_size,
                              hipStream_t stream) {
    const float* x  = (const float*)d_in[0];   // (1,128,56,56) f32
    const float* Wt = (const float*)d_in[1];   // (32,64,3) f32
    float* out = (float*)d_out;                // (1,32,56,56) f32

    dim3 grid(49, CI / NI), block(256);
    hipLaunchKernelGGL(convshift_kernel, grid, block, 0, stream, x, Wt, out);
}